// Round 1
// baseline (468.385 us; speedup 1.0000x reference)
//
#include <hip/hip_runtime.h>

#define DEG 32
#define DIMF 128
#define NH 4

// ---------- bf16 helpers (bit manip, round-to-nearest-even) ----------
__device__ __forceinline__ float bf2f(unsigned short u) {
    union { float f; unsigned u32; } v; v.u32 = ((unsigned)u) << 16; return v.f;
}
__device__ __forceinline__ unsigned short f2bf(float f) {
    union { float f; unsigned u32; } v; v.f = f;
    unsigned x = v.u32;
    x += ((x >> 16) & 1u) + 0x7FFFu;
    return (unsigned short)(x >> 16);
}

// ---------------------------------------------------------------------
// K1: WH[n, head*128+col] = sum_i h[n,i] * W[head][i][col], stored bf16.
// Block: 256 thr, 64 nodes, 8 chunks of 64 cols. f32 vector GEMM 4x4 microkernel.
// ---------------------------------------------------------------------
__global__ __launch_bounds__(256) void k1_wh(const float* __restrict__ h,
                                             const float* __restrict__ W,
                                             unsigned short* __restrict__ WH,
                                             int N) {
    __shared__ float hs[64][132];   // +4 pad: bank spread, 16B-aligned rows
    __shared__ float Wl[128][68];
    const int t = threadIdx.x;
    const int n0 = blockIdx.x * 64;

    // stage h tile 64x128
    for (int pass = 0; pass < 8; ++pass) {
        int idx = pass * 1024 + t * 4;
        int node = idx >> 7, k = idx & 127;
        float4 v = make_float4(0.f, 0.f, 0.f, 0.f);
        if (n0 + node < N) v = *(const float4*)&h[(size_t)(n0 + node) * 128 + k];
        *(float4*)&hs[node][k] = v;
    }

    const int ty = t >> 4, tx = t & 15;
    for (int chunk = 0; chunk < 8; ++chunk) {
        const int head = chunk >> 1, colb = (chunk & 1) * 64;
        __syncthreads();
        // stage W chunk 128x64
        for (int pass = 0; pass < 8; ++pass) {
            int idx = pass * 1024 + t * 4;
            int k = idx >> 6, cc = idx & 63;
            float4 v = *(const float4*)&W[(size_t)head * 16384 + k * 128 + colb + cc];
            *(float4*)&Wl[k][cc] = v;
        }
        __syncthreads();

        float acc[4][4];
        for (int i = 0; i < 4; ++i)
            for (int j = 0; j < 4; ++j) acc[i][j] = 0.f;

        for (int k4 = 0; k4 < 32; ++k4) {
            float4 a[4], b[4];
            for (int i = 0; i < 4; ++i) a[i] = *(const float4*)&hs[ty * 4 + i][k4 * 4];
            for (int kk = 0; kk < 4; ++kk) b[kk] = *(const float4*)&Wl[k4 * 4 + kk][tx * 4];
            for (int kk = 0; kk < 4; ++kk) {
                float4 bv = b[kk];
                for (int i = 0; i < 4; ++i) {
                    float av = ((const float*)&a[i])[kk];
                    acc[i][0] += av * bv.x;
                    acc[i][1] += av * bv.y;
                    acc[i][2] += av * bv.z;
                    acc[i][3] += av * bv.w;
                }
            }
        }
        for (int i = 0; i < 4; ++i) {
            int n = n0 + ty * 4 + i;
            if (n < N) {
                ushort4 o;
                o.x = f2bf(acc[i][0]); o.y = f2bf(acc[i][1]);
                o.z = f2bf(acc[i][2]); o.w = f2bf(acc[i][3]);
                *(ushort4*)&WH[(size_t)n * 512 + chunk * 64 + tx * 4] = o;
            }
        }
    }
}

// ---------------------------------------------------------------------
// K2: s1[n,k] = WH[n,k,:].a1[k] ; s2[n,k] = WH[n,k,:].a2[k] ; g = softmax(h@Wg)
// One wave per node. Lane l holds WH cols 8l..8l+7 (head = l>>4).
// ---------------------------------------------------------------------
__global__ __launch_bounds__(256) void k2_sg(const float* __restrict__ h,
                                             const unsigned short* __restrict__ WH,
                                             const float* __restrict__ a1,
                                             const float* __restrict__ a2,
                                             const float* __restrict__ Wg,
                                             float* __restrict__ s1,
                                             float* __restrict__ s2,
                                             float* __restrict__ g,
                                             int N) {
    const int wave = threadIdx.x >> 6;
    const int lane = threadIdx.x & 63;
    const int n = blockIdx.x * 4 + wave;
    if (n >= N) return;
    const int head = lane >> 4;
    const int c8 = (lane & 15) * 8;

    const unsigned short* row = WH + (size_t)n * 512 + lane * 8;
    ushort4 w0 = *(const ushort4*)row;
    ushort4 w1 = *(const ushort4*)(row + 4);
    float wf[8] = {bf2f(w0.x), bf2f(w0.y), bf2f(w0.z), bf2f(w0.w),
                   bf2f(w1.x), bf2f(w1.y), bf2f(w1.z), bf2f(w1.w)};
    const float* A1 = a1 + head * 128 + c8;
    const float* A2 = a2 + head * 128 + c8;
    float p1 = 0.f, p2 = 0.f;
    for (int e = 0; e < 8; ++e) { p1 += wf[e] * A1[e]; p2 += wf[e] * A2[e]; }
    for (int m = 8; m >= 1; m >>= 1) {
        p1 += __shfl_xor(p1, m, 16);
        p2 += __shfl_xor(p2, m, 16);
    }
    if ((lane & 15) == 0) { s1[n * 4 + head] = p1; s2[n * 4 + head] = p2; }

    // gate
    float2 hv = *(const float2*)&h[(size_t)n * 128 + lane * 2];
    float4 wg0 = *(const float4*)&Wg[(lane * 2) * 4];
    float4 wg1 = *(const float4*)&Wg[(lane * 2 + 1) * 4];
    float z0 = hv.x * wg0.x + hv.y * wg1.x;
    float z1 = hv.x * wg0.y + hv.y * wg1.y;
    float z2 = hv.x * wg0.z + hv.y * wg1.z;
    float z3 = hv.x * wg0.w + hv.y * wg1.w;
    for (int m = 32; m >= 1; m >>= 1) {
        z0 += __shfl_xor(z0, m, 64);
        z1 += __shfl_xor(z1, m, 64);
        z2 += __shfl_xor(z2, m, 64);
        z3 += __shfl_xor(z3, m, 64);
    }
    if (lane == 0) {
        float mx = fmaxf(fmaxf(z0, z1), fmaxf(z2, z3));
        float e0 = __expf(z0 - mx), e1 = __expf(z1 - mx);
        float e2 = __expf(z2 - mx), e3 = __expf(z3 - mx);
        float si = 1.f / (e0 + e1 + e2 + e3);
        float4 gv = make_float4(e0 * si, e1 * si, e2 * si, e3 * si);
        *(float4*)&g[n * 4] = gv;
    }
}

// ---------------------------------------------------------------------
// K3: per node: softmax over 32 neighbor scores per head, PV gather.
// Block 256 = 2 nodes; waves (0,1)->node0 heads(0,1 / 2,3), waves(2,3)->node1.
// Wave w: half = lane>>5 -> head 2*(w&1)+half; each lane loads ushort4 (4 cols).
// ---------------------------------------------------------------------
__global__ __launch_bounds__(256) void k3_attn(const int* __restrict__ idx,
                                               const unsigned short* __restrict__ WH,
                                               const float* __restrict__ s1,
                                               const float* __restrict__ s2,
                                               const float* __restrict__ g,
                                               unsigned short* __restrict__ T,
                                               int N) {
    __shared__ int jarr[2][32];
    const int t = threadIdx.x;
    const int wave = t >> 6;
    const int lane = t & 63;
    const int nodeSel = wave >> 1;
    const int w = wave & 1;
    const int n = blockIdx.x * 2 + nodeSel;

    if (t < 64) {
        int nn = blockIdx.x * 2 + (t >> 5);
        jarr[t >> 5][t & 31] = (nn < N) ? idx[(size_t)nn * 32 + (t & 31)] : 0;
    }
    __syncthreads();
    if (n >= N) return;

    const int half = lane >> 5;
    const int ld = lane & 31;
    const int head = w * 2 + half;

    // score + softmax (width-32 groups; each half-wave independent)
    int jl = jarr[nodeSel][ld];
    float e = s1[n * 4 + head] + s2[(size_t)jl * 4 + head];
    e = (e >= 0.f) ? e : 0.01f * e;
    float m = e;
    for (int mm = 16; mm >= 1; mm >>= 1) m = fmaxf(m, __shfl_xor(m, mm, 32));
    float p = __expf(e - m);
    float s = p;
    for (int mm = 16; mm >= 1; mm >>= 1) s += __shfl_xor(s, mm, 32);
    float att = p / s;

    // PV: acc over 4 bf16 cols per lane
    float acc0 = 0.f, acc1 = 0.f, acc2 = 0.f, acc3 = 0.f;
    const unsigned short* base = WH + w * 256 + half * 128 + ld * 4;
    for (int d = 0; d < 32; ++d) {
        int j = jarr[nodeSel][d];
        float ad = __shfl(att, (lane & 32) + d, 64);
        ushort4 v = *(const ushort4*)(base + (size_t)j * 512);
        acc0 += ad * bf2f(v.x);
        acc1 += ad * bf2f(v.y);
        acc2 += ad * bf2f(v.z);
        acc3 += ad * bf2f(v.w);
    }
    float gv = g[n * 4 + head];
    acc0 = fmaxf(acc0, 0.f) * gv;
    acc1 = fmaxf(acc1, 0.f) * gv;
    acc2 = fmaxf(acc2, 0.f) * gv;
    acc3 = fmaxf(acc3, 0.f) * gv;
    ushort4 o;
    o.x = f2bf(acc0); o.y = f2bf(acc1); o.z = f2bf(acc2); o.w = f2bf(acc3);
    *(ushort4*)&T[(size_t)n * 512 + head * 128 + ld * 4] = o;
}

// ---------------------------------------------------------------------
// K4: out[N,128] = T[N,512](bf16) @ W0[512,128](f32). 64-node x 64-col blocks,
// K chunked by 128. Same 4x4 microkernel as K1.
// ---------------------------------------------------------------------
__global__ __launch_bounds__(256) void k4_out(const unsigned short* __restrict__ T,
                                              const float* __restrict__ W0,
                                              float* __restrict__ out,
                                              int N) {
    __shared__ float Ts[64][132];
    __shared__ float W0s[128][68];
    const int t = threadIdx.x;
    const int n0 = blockIdx.x * 64;
    const int cy = blockIdx.y;          // col half: 0 or 1
    const int ty = t >> 4, tx = t & 15;

    float acc[4][4];
    for (int i = 0; i < 4; ++i)
        for (int j = 0; j < 4; ++j) acc[i][j] = 0.f;

    for (int kc = 0; kc < 4; ++kc) {
        __syncthreads();
        // stage T chunk 64x128 (bf16 -> f32)
        for (int pass = 0; pass < 8; ++pass) {
            int idx = pass * 1024 + t * 4;
            int node = idx >> 7, k = idx & 127;
            float4 f = make_float4(0.f, 0.f, 0.f, 0.f);
            if (n0 + node < N) {
                ushort4 v = *(const ushort4*)&T[(size_t)(n0 + node) * 512 + kc * 128 + k];
                f.x = bf2f(v.x); f.y = bf2f(v.y); f.z = bf2f(v.z); f.w = bf2f(v.w);
            }
            *(float4*)&Ts[node][k] = f;
        }
        // stage W0 chunk 128x64
        for (int pass = 0; pass < 8; ++pass) {
            int idx = pass * 1024 + t * 4;
            int k = idx >> 6, cc = idx & 63;
            float4 v = *(const float4*)&W0[(size_t)(kc * 128 + k) * 128 + cy * 64 + cc];
            *(float4*)&W0s[k][cc] = v;
        }
        __syncthreads();

        for (int k4 = 0; k4 < 32; ++k4) {
            float4 a[4], b[4];
            for (int i = 0; i < 4; ++i) a[i] = *(const float4*)&Ts[ty * 4 + i][k4 * 4];
            for (int kk = 0; kk < 4; ++kk) b[kk] = *(const float4*)&W0s[k4 * 4 + kk][tx * 4];
            for (int kk = 0; kk < 4; ++kk) {
                float4 bv = b[kk];
                for (int i = 0; i < 4; ++i) {
                    float av = ((const float*)&a[i])[kk];
                    acc[i][0] += av * bv.x;
                    acc[i][1] += av * bv.y;
                    acc[i][2] += av * bv.z;
                    acc[i][3] += av * bv.w;
                }
            }
        }
    }
    for (int i = 0; i < 4; ++i) {
        int n = n0 + ty * 4 + i;
        if (n < N) {
            float4 o = make_float4(acc[i][0], acc[i][1], acc[i][2], acc[i][3]);
            *(float4*)&out[(size_t)n * 128 + cy * 64 + tx * 4] = o;
        }
    }
}

// ---------------------------------------------------------------------
extern "C" void kernel_launch(void* const* d_in, const int* in_sizes, int n_in,
                              void* d_out, int out_size, void* d_ws, size_t ws_size,
                              hipStream_t stream) {
    const float* h     = (const float*)d_in[0];
    const int*   neigh = (const int*)d_in[1];
    const float* W     = (const float*)d_in[2];
    const float* a1    = (const float*)d_in[3];
    const float* a2    = (const float*)d_in[4];
    const float* Wg    = (const float*)d_in[5];
    const float* W0    = (const float*)d_in[6];
    float* out = (float*)d_out;

    const int N = in_sizes[0] / DIMF;

    char* ws = (char*)d_ws;
    unsigned short* WH = (unsigned short*)ws;                               // N*512*2 B
    unsigned short* T  = (unsigned short*)(ws + (size_t)N * 512 * 2);       // N*512*2 B
    float* s1 = (float*)(ws + (size_t)N * 512 * 4);                          // N*4 f32
    float* s2 = s1 + (size_t)N * 4;
    float* g  = s2 + (size_t)N * 4;

    k1_wh<<<dim3((N + 63) / 64), dim3(256), 0, stream>>>(h, W, WH, N);
    k2_sg<<<dim3((N + 3) / 4), dim3(256), 0, stream>>>(h, WH, a1, a2, Wg, s1, s2, g, N);
    k3_attn<<<dim3((N + 1) / 2), dim3(256), 0, stream>>>(neigh, WH, s1, s2, g, T, N);
    k4_out<<<dim3((N + 63) / 64, 2), dim3(256), 0, stream>>>(T, W0, out, N);
}

// Round 2
// 330.126 us; speedup vs baseline: 1.4188x; 1.4188x over previous
//
#include <hip/hip_runtime.h>

#define NDEG 32

typedef __attribute__((ext_vector_type(8))) short short8;
typedef __attribute__((ext_vector_type(4))) float f32x4;

// ---------- bf16 helpers (bit manip, round-to-nearest-even) ----------
__device__ __forceinline__ float bf2f(unsigned short u) {
    union { float f; unsigned u32; } v; v.u32 = ((unsigned)u) << 16; return v.f;
}
__device__ __forceinline__ unsigned short f2bf(float f) {
    union { float f; unsigned u32; } v; v.f = f;
    unsigned x = v.u32;
    x += ((x >> 16) & 1u) + 0x7FFFu;
    return (unsigned short)(x >> 16);
}

// ---------------------------------------------------------------------
// kconv: blocks [0,hblocks): h f32 -> hb bf16.  blocks [hblocks, +256):
// W[4][128][128] -> Wt[4][col][k] bf16 (transposed per head).
// ---------------------------------------------------------------------
__global__ __launch_bounds__(256) void kconv(const float* __restrict__ h,
                                             const float* __restrict__ W,
                                             unsigned short* __restrict__ hb,
                                             unsigned short* __restrict__ Wt,
                                             int N, int hblocks) {
    int b = blockIdx.x;
    if (b < hblocks) {
        size_t i = (size_t)b * 1024 + threadIdx.x * 4;
        size_t total = (size_t)N * 128;
        if (i + 3 < total) {
            float4 v = *(const float4*)&h[i];
            ushort4 o;
            o.x = f2bf(v.x); o.y = f2bf(v.y); o.z = f2bf(v.z); o.w = f2bf(v.w);
            *(ushort4*)&hb[i] = o;
        } else {
            for (int e = 0; e < 4; ++e) if (i + e < total) hb[i + e] = f2bf(h[i + e]);
        }
    } else {
        int idx = (b - hblocks) * 256 + threadIdx.x;   // [0, 65536)
        int head = idx >> 14, rem = idx & 16383, k = rem >> 7, col = rem & 127;
        Wt[head * 16384 + col * 128 + k] = f2bf(W[idx]);
    }
}

// kconv2: W0[512][128] -> W0t[col][k] bf16 [128][512]
__global__ __launch_bounds__(256) void kconv2(const float* __restrict__ W0,
                                              unsigned short* __restrict__ W0t) {
    int idx = blockIdx.x * 256 + threadIdx.x;   // [0, 65536)
    int k = idx >> 7, col = idx & 127;
    W0t[col * 512 + k] = f2bf(W0[idx]);
}

// ---------------------------------------------------------------------
// K1: WH[n, head*128+c] = sum_k hb[n,k] * W[head][k][c]  via MFMA bf16.
// grid (N/64, 4 heads), 256 thr (4 waves x 16 rows). Fused epilogue:
// s1[n,head] = WH_f32 . a1[head],  s2 likewise (f32 accum, pre-rounding).
// LDS tiles XOR-swizzled (byte ^= (row&7)<<4) for conflict-free ds_read_b128.
// ---------------------------------------------------------------------
__global__ __launch_bounds__(256) void k1_mfma(const unsigned short* __restrict__ hb,
                                               const unsigned short* __restrict__ Wt,
                                               const float* __restrict__ a1,
                                               const float* __restrict__ a2,
                                               unsigned short* __restrict__ WH,
                                               float* __restrict__ s1,
                                               float* __restrict__ s2,
                                               int N) {
    __shared__ unsigned short Al[64 * 128];    // 16 KB, swizzled [row][k]
    __shared__ unsigned short Bl[128 * 128];   // 32 KB, swizzled [col][k]
    const int t = threadIdx.x;
    const int n0 = blockIdx.x * 64;
    const int head = blockIdx.y;

    // stage A (hb rows n0..n0+63)
    #pragma unroll
    for (int p = 0; p < 4; ++p) {
        int lin = p * 4096 + t * 16;           // byte offset, rows of 256B
        int row = lin >> 8;
        int cb = lin & 255;
        short8 v = {};
        int n = n0 + row;
        if (n < N) v = *(const short8*)&hb[(size_t)n * 128 + (cb >> 1)];
        *(short8*)((char*)Al + (lin ^ ((row & 7) << 4))) = v;
    }
    // stage B (Wt[head], 128 cols x 128 k)
    #pragma unroll
    for (int p = 0; p < 8; ++p) {
        int lin = p * 4096 + t * 16;
        int row = lin >> 8;                    // col index
        int cb = lin & 255;
        short8 v = *(const short8*)&Wt[(size_t)head * 16384 + row * 128 + (cb >> 1)];
        *(short8*)((char*)Bl + (lin ^ ((row & 7) << 4))) = v;
    }
    __syncthreads();

    const int w = t >> 6, l = t & 63;
    const int l15 = l & 15, lh = l >> 4;
    f32x4 acc[8] = {};
    const char* Ab = (const char*)Al;
    const char* Bb = (const char*)Bl;
    #pragma unroll
    for (int s = 0; s < 4; ++s) {
        const int arow = w * 16 + l15;
        const int abyte = (arow << 8) + s * 64 + lh * 16;
        short8 af = *(const short8*)(Ab + (abyte ^ ((arow & 7) << 4)));
        #pragma unroll
        for (int cg = 0; cg < 8; ++cg) {
            const int brow = cg * 16 + l15;
            const int bbyte = (brow << 8) + s * 64 + lh * 16;
            short8 bf = *(const short8*)(Bb + (bbyte ^ ((brow & 7) << 4)));
            acc[cg] = __builtin_amdgcn_mfma_f32_16x16x32_bf16(af, bf, acc[cg], 0, 0, 0);
        }
    }

    // epilogue: WH store + fused s1/s2
    float a1v[8], a2v[8];
    #pragma unroll
    for (int cg = 0; cg < 8; ++cg) {
        a1v[cg] = a1[head * 128 + cg * 16 + l15];
        a2v[cg] = a2[head * 128 + cg * 16 + l15];
    }
    float p1[4] = {0.f, 0.f, 0.f, 0.f}, p2[4] = {0.f, 0.f, 0.f, 0.f};
    #pragma unroll
    for (int cg = 0; cg < 8; ++cg) {
        #pragma unroll
        for (int r = 0; r < 4; ++r) {
            float v = acc[cg][r];
            p1[r] += v * a1v[cg];
            p2[r] += v * a2v[cg];
            int n = n0 + w * 16 + lh * 4 + r;
            if (n < N)
                WH[(size_t)n * 512 + head * 128 + cg * 16 + l15] = f2bf(v);
        }
    }
    #pragma unroll
    for (int r = 0; r < 4; ++r) {
        #pragma unroll
        for (int m = 8; m >= 1; m >>= 1) {
            p1[r] += __shfl_xor(p1[r], m, 16);
            p2[r] += __shfl_xor(p2[r], m, 16);
        }
    }
    if (l15 == 0) {
        #pragma unroll
        for (int r = 0; r < 4; ++r) {
            int n = n0 + w * 16 + lh * 4 + r;
            if (n < N) { s1[n * 4 + head] = p1[r]; s2[n * 4 + head] = p2[r]; }
        }
    }
}

// ---------------------------------------------------------------------
// kgate: g = softmax(h @ Wg). One wave per node.
// ---------------------------------------------------------------------
__global__ __launch_bounds__(256) void kgate(const float* __restrict__ h,
                                             const float* __restrict__ Wg,
                                             float* __restrict__ g,
                                             int N) {
    const int wave = threadIdx.x >> 6;
    const int lane = threadIdx.x & 63;
    const int n = blockIdx.x * 4 + wave;
    if (n >= N) return;

    float2 hv = *(const float2*)&h[(size_t)n * 128 + lane * 2];
    float4 wg0 = *(const float4*)&Wg[(lane * 2) * 4];
    float4 wg1 = *(const float4*)&Wg[(lane * 2 + 1) * 4];
    float z0 = hv.x * wg0.x + hv.y * wg1.x;
    float z1 = hv.x * wg0.y + hv.y * wg1.y;
    float z2 = hv.x * wg0.z + hv.y * wg1.z;
    float z3 = hv.x * wg0.w + hv.y * wg1.w;
    #pragma unroll
    for (int m = 32; m >= 1; m >>= 1) {
        z0 += __shfl_xor(z0, m, 64);
        z1 += __shfl_xor(z1, m, 64);
        z2 += __shfl_xor(z2, m, 64);
        z3 += __shfl_xor(z3, m, 64);
    }
    if (lane == 0) {
        float mx = fmaxf(fmaxf(z0, z1), fmaxf(z2, z3));
        float e0 = __expf(z0 - mx), e1 = __expf(z1 - mx);
        float e2 = __expf(z2 - mx), e3 = __expf(z3 - mx);
        float si = 1.f / (e0 + e1 + e2 + e3);
        float4 gv = make_float4(e0 * si, e1 * si, e2 * si, e3 * si);
        *(float4*)&g[n * 4] = gv;
    }
}

// ---------------------------------------------------------------------
// K3: one node per wave. Phase 1: scores + softmax (2 heads per lane via
// half split). Phase 2: PV gather, full 1KB row per wave-iter (dwordx4/lane),
// fully unrolled for MLP. T[n] = g * relu(sum att*WH[j]).
// ---------------------------------------------------------------------
__global__ __launch_bounds__(256) void k3_attn(const int* __restrict__ idx,
                                               const unsigned short* __restrict__ WH,
                                               const float* __restrict__ s1,
                                               const float* __restrict__ s2,
                                               const float* __restrict__ g,
                                               unsigned short* __restrict__ T,
                                               int N) {
    __shared__ float att[4][4][33];
    const int t = threadIdx.x, w = t >> 6, l = t & 63;
    int n = blockIdx.x * 4 + w;
    const bool valid = (n < N);
    if (!valid) n = N - 1;                 // clamp; no early return (barrier below)
    const int d = l & 31, half = l >> 5;

    int j = idx[(size_t)n * 32 + d];
    float2 s2v = *(const float2*)&s2[(size_t)j * 4 + half * 2];
    const float* s1p = &s1[(size_t)n * 4];
    float e0 = s1p[half * 2] + s2v.x;
    float e1 = s1p[half * 2 + 1] + s2v.y;
    e0 = (e0 >= 0.f) ? e0 : 0.01f * e0;
    e1 = (e1 >= 0.f) ? e1 : 0.01f * e1;
    float m0 = e0, m1 = e1;
    #pragma unroll
    for (int mm = 16; mm >= 1; mm >>= 1) {
        m0 = fmaxf(m0, __shfl_xor(m0, mm, 32));
        m1 = fmaxf(m1, __shfl_xor(m1, mm, 32));
    }
    float p0 = __expf(e0 - m0), p1 = __expf(e1 - m1);
    float q0 = p0, q1 = p1;
    #pragma unroll
    for (int mm = 16; mm >= 1; mm >>= 1) {
        q0 += __shfl_xor(q0, mm, 32);
        q1 += __shfl_xor(q1, mm, 32);
    }
    att[w][half * 2][d] = p0 / q0;
    att[w][half * 2 + 1][d] = p1 / q1;
    __syncthreads();

    const int hsel = l >> 4;
    const unsigned short* base = WH + (size_t)l * 8;
    float acc0 = 0.f, acc1 = 0.f, acc2 = 0.f, acc3 = 0.f;
    float acc4 = 0.f, acc5 = 0.f, acc6 = 0.f, acc7 = 0.f;
    #pragma unroll
    for (int dd = 0; dd < 32; ++dd) {
        int jj = __shfl(j, dd, 64);
        float a = att[w][hsel][dd];
        short8 v = *(const short8*)(base + (size_t)jj * 512);
        acc0 += a * bf2f((unsigned short)v[0]);
        acc1 += a * bf2f((unsigned short)v[1]);
        acc2 += a * bf2f((unsigned short)v[2]);
        acc3 += a * bf2f((unsigned short)v[3]);
        acc4 += a * bf2f((unsigned short)v[4]);
        acc5 += a * bf2f((unsigned short)v[5]);
        acc6 += a * bf2f((unsigned short)v[6]);
        acc7 += a * bf2f((unsigned short)v[7]);
    }
    float4 gv4 = *(const float4*)&g[(size_t)n * 4];
    float gv = (hsel == 0) ? gv4.x : (hsel == 1) ? gv4.y : (hsel == 2) ? gv4.z : gv4.w;
    short8 o;
    o[0] = (short)f2bf(fmaxf(acc0, 0.f) * gv);
    o[1] = (short)f2bf(fmaxf(acc1, 0.f) * gv);
    o[2] = (short)f2bf(fmaxf(acc2, 0.f) * gv);
    o[3] = (short)f2bf(fmaxf(acc3, 0.f) * gv);
    o[4] = (short)f2bf(fmaxf(acc4, 0.f) * gv);
    o[5] = (short)f2bf(fmaxf(acc5, 0.f) * gv);
    o[6] = (short)f2bf(fmaxf(acc6, 0.f) * gv);
    o[7] = (short)f2bf(fmaxf(acc7, 0.f) * gv);
    if (valid) *(short8*)&T[(size_t)n * 512 + l * 8] = o;
}

// ---------------------------------------------------------------------
// K4: out[N,128] = T[N,512](bf16) @ W0[512,128] via MFMA. K chunked by 128.
// ---------------------------------------------------------------------
__global__ __launch_bounds__(256) void k4_mfma(const unsigned short* __restrict__ T,
                                               const unsigned short* __restrict__ W0t,
                                               float* __restrict__ out,
                                               int N) {
    __shared__ unsigned short Al[64 * 128];
    __shared__ unsigned short Bl[128 * 128];
    const int t = threadIdx.x;
    const int n0 = blockIdx.x * 64;
    const int w = t >> 6, l = t & 63;
    const int l15 = l & 15, lh = l >> 4;

    f32x4 acc[8] = {};
    for (int kc = 0; kc < 4; ++kc) {
        __syncthreads();
        #pragma unroll
        for (int p = 0; p < 4; ++p) {
            int lin = p * 4096 + t * 16;
            int row = lin >> 8, cb = lin & 255;
            short8 v = {};
            int n = n0 + row;
            if (n < N) v = *(const short8*)&T[(size_t)n * 512 + kc * 128 + (cb >> 1)];
            *(short8*)((char*)Al + (lin ^ ((row & 7) << 4))) = v;
        }
        #pragma unroll
        for (int p = 0; p < 8; ++p) {
            int lin = p * 4096 + t * 16;
            int row = lin >> 8, cb = lin & 255;
            short8 v = *(const short8*)&W0t[(size_t)row * 512 + kc * 128 + (cb >> 1)];
            *(short8*)((char*)Bl + (lin ^ ((row & 7) << 4))) = v;
        }
        __syncthreads();
        const char* Ab = (const char*)Al;
        const char* Bb = (const char*)Bl;
        #pragma unroll
        for (int s = 0; s < 4; ++s) {
            const int arow = w * 16 + l15;
            const int abyte = (arow << 8) + s * 64 + lh * 16;
            short8 af = *(const short8*)(Ab + (abyte ^ ((arow & 7) << 4)));
            #pragma unroll
            for (int cg = 0; cg < 8; ++cg) {
                const int brow = cg * 16 + l15;
                const int bbyte = (brow << 8) + s * 64 + lh * 16;
                short8 bf = *(const short8*)(Bb + (bbyte ^ ((brow & 7) << 4)));
                acc[cg] = __builtin_amdgcn_mfma_f32_16x16x32_bf16(af, bf, acc[cg], 0, 0, 0);
            }
        }
    }
    #pragma unroll
    for (int cg = 0; cg < 8; ++cg) {
        #pragma unroll
        for (int r = 0; r < 4; ++r) {
            int n = n0 + w * 16 + lh * 4 + r;
            if (n < N) out[(size_t)n * 128 + cg * 16 + l15] = acc[cg][r];
        }
    }
}

// ---------------------------------------------------------------------
extern "C" void kernel_launch(void* const* d_in, const int* in_sizes, int n_in,
                              void* d_out, int out_size, void* d_ws, size_t ws_size,
                              hipStream_t stream) {
    const float* h     = (const float*)d_in[0];
    const int*   neigh = (const int*)d_in[1];
    const float* W     = (const float*)d_in[2];
    const float* a1    = (const float*)d_in[3];
    const float* a2    = (const float*)d_in[4];
    const float* Wg    = (const float*)d_in[5];
    const float* W0    = (const float*)d_in[6];
    float* out = (float*)d_out;

    const int N = in_sizes[0] / 128;

    char* ws = (char*)d_ws;
    unsigned short* WH  = (unsigned short*)ws;                          // N*512 bf16
    unsigned short* Trg = (unsigned short*)(ws + (size_t)N * 1024);     // N*512 bf16
    // aliases into dead regions (sequenced by stream order):
    unsigned short* hb  = Trg;                                  // dead before k3 writes T
    unsigned short* Wt  = (unsigned short*)((char*)Trg + 13631488); // 128KB, dead before k3
    unsigned short* W0t = WH;                                   // written after k3 (WH dead)
    float* s1 = (float*)(ws + (size_t)N * 2048);
    float* s2 = s1 + (size_t)N * 4;
    float* g  = s2 + (size_t)N * 4;

    const int hblocks = (N * 128 + 1023) / 1024;
    kconv<<<dim3(hblocks + 256), dim3(256), 0, stream>>>(h, W, hb, Wt, N, hblocks);
    k1_mfma<<<dim3((N + 63) / 64, 4), dim3(256), 0, stream>>>(hb, Wt, a1, a2, WH, s1, s2, N);
    kgate<<<dim3((N + 3) / 4), dim3(256), 0, stream>>>(h, Wg, g, N);
    k3_attn<<<dim3((N + 3) / 4), dim3(256), 0, stream>>>(neigh, WH, s1, s2, g, Trg, N);
    kconv2<<<dim3(256), dim3(256), 0, stream>>>(W0, W0t);
    k4_mfma<<<dim3((N + 63) / 64), dim3(256), 0, stream>>>(Trg, W0t, out, N);
}